// Round 12
// baseline (169.274 us; speedup 1.0000x reference)
//
#include <hip/hip_runtime.h>
#include <hip/hip_bf16.h>
#include <cstdint>
#include <cstddef>

#define NB    1024
#define NF    32
#define DIN   64
#define HID   128
#define HEADS 4
#define NTOT  (NB*NF)
#define H1DIM (HEADS*HID)

typedef __attribute__((ext_vector_type(8))) short          bf16x8;
typedef __attribute__((ext_vector_type(8))) unsigned short u16x8;
typedef __attribute__((ext_vector_type(4))) float          f32x4;

__device__ __forceinline__ float bf2f(unsigned short u) {
    return __uint_as_float(((unsigned)u) << 16);
}
__device__ __forceinline__ unsigned short f2bf(float f) {
    unsigned u = __float_as_uint(f);
    return (unsigned short)((u + 0x7FFF + ((u >> 16) & 1)) >> 16);   // RNE
}

// swizzled LDS helpers (u16 element index; 16B-chunk XOR within 64B rows)
__device__ __forceinline__ int st128_at(int r, int k) {     // [128][32] u16
    return r * 32 + ((((k >> 3) ^ ((r >> 1) & 3)) & 3) << 3) + (k & 7);
}
__device__ __forceinline__ int st32_at(int r, int k) {      // [32][32] u16
    return r * 32 + ((((k >> 3) ^ ((r >> 1) & 3)) & 3) << 3) + (k & 7);
}

// ---------------------------------------------------------------------------
// weight prep (bf16 B^T): w1T[512][128], w2T[128][512], WaT[128][64]
// ---------------------------------------------------------------------------
__global__ __launch_bounds__(256) void k_prep(
    const float* __restrict__ w1, const float* __restrict__ w2,
    const float* __restrict__ Wa,
    unsigned short* __restrict__ w1T, unsigned short* __restrict__ w2T,
    unsigned short* __restrict__ WaT)
{
    int i = blockIdx.x * 256 + threadIdx.x;
    if (i < HID * H1DIM) {
        int n = i >> 7, k = i & 127;
        w1T[i] = f2bf(w1[k * H1DIM + n]);
    } else if (i < 2 * HID * H1DIM) {
        int j = i - HID * H1DIM;
        int n = j >> 9, k = j & 511;
        w2T[j] = f2bf(w2[k * HID + n]);
    } else {
        int j = i - 2 * HID * H1DIM;
        int c = j >> 6, k = j & 63;
        WaT[j] = f2bf(Wa[k * HID + c]);
    }
}

// ---------------------------------------------------------------------------
// aligner: MFMA GEMM (32 rows x 128, K=64) + bias + LN + gate
// ---------------------------------------------------------------------------
__global__ __launch_bounds__(256) void k_align(
    const float* __restrict__ xf, const unsigned short* __restrict__ WaT,
    const float* __restrict__ ba, const float* __restrict__ gamma,
    const float* __restrict__ beta, const float* __restrict__ gl,
    unsigned short* __restrict__ x0b)
{
    __shared__ char smem[23296];
    unsigned short* As = (unsigned short*)smem;            // [32][72]
    unsigned short* Ws = (unsigned short*)(smem + 4608);   // [128][72]
    float*          Cs = (float*)smem;                     // [32][132] reuse

    int t = threadIdx.x, l = t & 63, w = t >> 6;
    int r0 = blockIdx.x * 32;
    {
        int r = t >> 3, k0 = (t & 7) * 8;
        float4 a = *(const float4*)&xf[(size_t)(r0 + r) * DIN + k0];
        float4 b = *(const float4*)&xf[(size_t)(r0 + r) * DIN + k0 + 4];
        u16x8 v;
        v[0] = f2bf(a.x); v[1] = f2bf(a.y); v[2] = f2bf(a.z); v[3] = f2bf(a.w);
        v[4] = f2bf(b.x); v[5] = f2bf(b.y); v[6] = f2bf(b.z); v[7] = f2bf(b.w);
        *(u16x8*)&As[r * 72 + k0] = v;
    }
    for (int i = t; i < 128 * 8; i += 256) {
        int c = i >> 3, k0 = (i & 7) * 8;
        *(u16x8*)&Ws[c * 72 + k0] = *(const u16x8*)&WaT[c * 64 + k0];
    }
    __syncthreads();

    int wr = w >> 1, wc = w & 1;
    f32x4 acc[4];
    #pragma unroll
    for (int n = 0; n < 4; ++n) acc[n] = (f32x4){0.f, 0.f, 0.f, 0.f};
    bf16x8 af0 = *(const bf16x8*)&As[(wr * 16 + (l & 15)) * 72 + (l >> 4) * 8];
    bf16x8 af1 = *(const bf16x8*)&As[(wr * 16 + (l & 15)) * 72 + 32 + (l >> 4) * 8];
    #pragma unroll
    for (int n = 0; n < 4; ++n) {
        bf16x8 b0 = *(const bf16x8*)&Ws[(wc * 64 + n * 16 + (l & 15)) * 72 + (l >> 4) * 8];
        bf16x8 b1 = *(const bf16x8*)&Ws[(wc * 64 + n * 16 + (l & 15)) * 72 + 32 + (l >> 4) * 8];
        acc[n] = __builtin_amdgcn_mfma_f32_16x16x32_bf16(af0, b0, acc[n], 0, 0, 0);
        acc[n] = __builtin_amdgcn_mfma_f32_16x16x32_bf16(af1, b1, acc[n], 0, 0, 0);
    }
    __syncthreads();
    #pragma unroll
    for (int n = 0; n < 4; ++n)
        #pragma unroll
        for (int v = 0; v < 4; ++v)
            Cs[(wr * 16 + (l >> 4) * 4 + v) * 132 + wc * 64 + n * 16 + (l & 15)] = acc[n][v];
    __syncthreads();

    int row = t >> 3, p = t & 7;
    float vals[16];
    float s = 0.f, s2 = 0.f;
    #pragma unroll
    for (int j = 0; j < 16; ++j) {
        float vv = Cs[row * 132 + p * 16 + j] + ba[p * 16 + j];
        vals[j] = vv; s += vv; s2 += vv * vv;
    }
    #pragma unroll
    for (int o = 1; o < 8; o <<= 1) { s += __shfl_xor(s, o); s2 += __shfl_xor(s2, o); }
    float mu  = s * (1.0f / HID);
    float var = s2 * (1.0f / HID) - mu * mu;
    float rs  = rsqrtf(var + 1e-5f);
    float g   = 1.0f / (1.0f + __expf(-gl[row]));
    u16x8 o0, o1;
    #pragma unroll
    for (int j = 0; j < 8; ++j) {
        o0[j] = f2bf(((vals[j]     - mu) * rs * gamma[p * 16 + j]     + beta[p * 16 + j])     * g);
        o1[j] = f2bf(((vals[j + 8] - mu) * rs * gamma[p * 16 + j + 8] + beta[p * 16 + j + 8]) * g);
    }
    *(u16x8*)&x0b[(size_t)(r0 + row) * HID + p * 16]     = o0;
    *(u16x8*)&x0b[(size_t)(r0 + row) * HID + p * 16 + 8] = o1;
}

// ---------------------------------------------------------------------------
// GEMM1: h1 = x0 @ w1 (batched). Block = (head bx, 128-node tile by).
// Epilogue: complete es1/ed1 for (node, head) + h1t[b][f][s] packed store.
// ---------------------------------------------------------------------------
__global__ __launch_bounds__(256) void k_gemm1(
    const unsigned short* __restrict__ x0b, const unsigned short* __restrict__ w1T,
    const float* __restrict__ as1, const float* __restrict__ ad1,
    unsigned short* __restrict__ h1t, float* __restrict__ es1, float* __restrict__ ed1)
{
    __shared__ __align__(16) unsigned short As[128 * 32];
    __shared__ __align__(16) unsigned short Bs[128 * 32];
    __shared__ float esP[2][128], edP[2][128];

    const int bx = blockIdx.x, by = blockIdx.y;
    const int t = threadIdx.x, w = t >> 6, l = t & 63;
    const int wr = w >> 1, wc = w & 1;
    const int g = l >> 4, i16 = l & 15;
    const f32x4 zf4 = {0.f, 0.f, 0.f, 0.f};

    f32x4 acc[4][4];
    #pragma unroll
    for (int m = 0; m < 4; ++m)
        #pragma unroll
        for (int n = 0; n < 4; ++n) acc[m][n] = zf4;

    for (int k0 = 0; k0 < HID; k0 += 32) {
        for (int i = t; i < 512; i += 256) {
            int r = i >> 2, ch = (i & 3) * 8;
            *(u16x8*)&As[st128_at(r, ch)] =
                *(const u16x8*)&x0b[(size_t)(by * 128 + r) * HID + k0 + ch];
            *(u16x8*)&Bs[st128_at(r, ch)] =
                *(const u16x8*)&w1T[(size_t)(bx * 128 + r) * HID + k0 + ch];
        }
        __syncthreads();
        bf16x8 aF[4], bF[4];
        #pragma unroll
        for (int m = 0; m < 4; ++m)
            aF[m] = *(const bf16x8*)&As[st128_at(wr * 64 + m * 16 + i16, g * 8)];
        #pragma unroll
        for (int n = 0; n < 4; ++n)
            bF[n] = *(const bf16x8*)&Bs[st128_at(wc * 64 + n * 16 + i16, g * 8)];
        #pragma unroll
        for (int m = 0; m < 4; ++m)
            #pragma unroll
            for (int n = 0; n < 4; ++n)
                acc[m][n] = __builtin_amdgcn_mfma_f32_16x16x32_bf16(aF[m], bF[n], acc[m][n], 0, 0, 0);
        __syncthreads();
    }

    // logits (complete for this head): reduce over i16, cross-wc via LDS
    {
        float asv[4], adv[4];
        #pragma unroll
        for (int n = 0; n < 4; ++n) {
            int f = bx * 128 + wc * 64 + n * 16 + i16;
            asv[n] = as1[f]; adv[n] = ad1[f];
        }
        float pe[4][4], pd[4][4];
        #pragma unroll
        for (int m = 0; m < 4; ++m)
            #pragma unroll
            for (int v = 0; v < 4; ++v) {
                float e = 0.f, d = 0.f;
                #pragma unroll
                for (int n = 0; n < 4; ++n) {
                    e = fmaf(acc[m][n][v], asv[n], e);
                    d = fmaf(acc[m][n][v], adv[n], d);
                }
                pe[m][v] = e; pd[m][v] = d;
            }
        #pragma unroll
        for (int o = 1; o < 16; o <<= 1) {
            #pragma unroll
            for (int m = 0; m < 4; ++m)
                #pragma unroll
                for (int v = 0; v < 4; ++v) {
                    pe[m][v] += __shfl_xor(pe[m][v], o);
                    pd[m][v] += __shfl_xor(pd[m][v], o);
                }
        }
        if (i16 == 0) {
            #pragma unroll
            for (int m = 0; m < 4; ++m)
                #pragma unroll
                for (int v = 0; v < 4; ++v) {
                    int rl = wr * 64 + m * 16 + g * 4 + v;
                    esP[wc][rl] = pe[m][v];
                    edP[wc][rl] = pd[m][v];
                }
        }
    }
    // h1t packed store: h1t[(gb*512 + f)*32 + s]
    #pragma unroll
    for (int m = 0; m < 4; ++m)
        #pragma unroll
        for (int n = 0; n < 4; ++n) {
            int node0 = by * 128 + wr * 64 + m * 16 + g * 4;
            int gb = node0 >> 5, s0 = node0 & 31;
            int f = bx * 128 + wc * 64 + n * 16 + i16;
            unsigned d0 = (unsigned)f2bf(acc[m][n][0]) | ((unsigned)f2bf(acc[m][n][1]) << 16);
            unsigned d1 = (unsigned)f2bf(acc[m][n][2]) | ((unsigned)f2bf(acc[m][n][3]) << 16);
            uint2 pk = {d0, d1};
            *(uint2*)&h1t[((size_t)gb * 512 + f) * 32 + s0] = pk;
        }
    __syncthreads();
    if (t < 128) {
        int node = by * 128 + t;
        es1[(size_t)node * HEADS + bx] = esP[0][t] + esP[1][t];
        ed1[(size_t)node * HEADS + bx] = edP[0][t] + edP[1][t];
    }
}

// ---------------------------------------------------------------------------
// GAT1: per graph. cnt | softmax1 | PV via MFMA (h1t read direct-global,
// coalesced) | ELU | x1 row-major out via 16KB half-bounce.
// LDS 25088 B -> 6 blocks/CU.
// ---------------------------------------------------------------------------
__global__ __launch_bounds__(256) void k_gat1(
    const unsigned short* __restrict__ h1t, const float* __restrict__ es1,
    const float* __restrict__ ed1, const float* __restrict__ b1,
    const int* __restrict__ src, const int* __restrict__ dst, int epg,
    unsigned short* __restrict__ x1g)
{
    __shared__ __align__(16) char S[25088];
    unsigned short* x1Lh   = (unsigned short*)S;             // [32][256] (out)
    int*            cntI   = (int*)S;                        // [1024] (P0)
    unsigned char*  cntB   = (unsigned char*)(S + 4096);
    float*          esL    = (float*)(S + 5120);             // [128] (d*4+h)
    float*          edL    = (float*)(S + 5632);
    unsigned short* alphaL = (unsigned short*)(S + 16384);   // [4][32][32]
    float*          rsumL  = (float*)(S + 24576);            // [128] h*32+d

    const int b = blockIdx.x, t = threadIdx.x;
    const int w = t >> 6, l = t & 63;
    const int g = l >> 4, i16 = l & 15;
    const int nb = b * NF;
    const f32x4 zf4 = {0.f, 0.f, 0.f, 0.f};

    for (int i = t; i < NF * NF; i += 256) cntI[i] = 0;
    __syncthreads();
    for (int i = t; i < epg; i += 256) {
        int sv = src[b * epg + i] - nb;
        int dv = dst[b * epg + i] - nb;
        atomicAdd(&cntI[dv * NF + sv], 1);
    }
    if (t < NF) atomicAdd(&cntI[t * 33], 1);
    __syncthreads();
    for (int i = t; i < NF * NF; i += 256) {
        int c = cntI[i];
        cntB[i] = (unsigned char)(c > 255 ? 255 : c);
    }
    if (t < 128) {
        esL[t] = es1[(size_t)nb * HEADS + t];
        edL[t] = ed1[(size_t)nb * HEADS + t];
    }
    __syncthreads();

    // softmax: thread (d,h)
    if (t < 128) {
        int d = t >> 2, h = t & 3;
        float edv = edL[d * 4 + h];
        float mx = -INFINITY;
        #pragma unroll
        for (int s = 0; s < NF; ++s) {
            if (cntB[d * NF + s]) {
                float lg = esL[s * 4 + h] + edv;
                lg = fmaxf(lg, 0.2f * lg);
                mx = fmaxf(mx, lg);
            }
        }
        float sum = 0.f;
        #pragma unroll
        for (int s = 0; s < NF; ++s) {
            int c = cntB[d * NF + s];
            float a = 0.f;
            if (c) {
                float lg = esL[s * 4 + h] + edv;
                lg = fmaxf(lg, 0.2f * lg);
                a = (float)c * __expf(lg - mx);
                sum += a;
            }
            alphaL[h * 1024 + st32_at(d, s)] = f2bf(a);
        }
        rsumL[h * 32 + d] = 1.0f / sum;
    }
    __syncthreads();

    // PV: wave = head w; B-frags direct from global h1t (coalesced 1KB/inst)
    f32x4 po[2][8];
    {
        bf16x8 aF2[2];
        #pragma unroll
        for (int m = 0; m < 2; ++m)
            aF2[m] = *(const bf16x8*)&alphaL[w * 1024 + st32_at(m * 16 + i16, g * 8)];
        #pragma unroll
        for (int n = 0; n < 8; ++n) {
            bf16x8 bF = *(const bf16x8*)&h1t[((size_t)b * 512 + w * 128 + n * 16 + i16) * 32 + g * 8];
            #pragma unroll
            for (int m = 0; m < 2; ++m)
                po[m][n] = __builtin_amdgcn_mfma_f32_16x16x32_bf16(aF2[m], bF, zf4, 0, 0, 0);
        }
    }

    // two output rounds: heads {0,1} then {2,3}; 16KB bounce each
    #pragma unroll
    for (int ro = 0; ro < 2; ++ro) {
        if ((w >> 1) == ro) {
            #pragma unroll
            for (int m = 0; m < 2; ++m)
                #pragma unroll
                for (int n = 0; n < 8; ++n) {
                    int cr = (w & 1) * 128 + n * 16 + i16;
                    float bias = b1[w * 128 + n * 16 + i16];
                    #pragma unroll
                    for (int v = 0; v < 4; ++v) {
                        int r = m * 16 + g * 4 + v;
                        float x = po[m][n][v] * rsumL[w * 32 + r] + bias;
                        x = (x > 0.f) ? x : (__expf(x) - 1.0f);
                        x1Lh[r * 256 + cr] = f2bf(x);
                    }
                }
        }
        __syncthreads();
        #pragma unroll
        for (int j = 0; j < 4; ++j) {
            int idx = j * 256 + t;
            int r = idx >> 5, ch = (idx & 31) * 8;
            u16x8 vv = *(const u16x8*)&x1Lh[r * 256 + ch];
            *(u16x8*)&x1g[(size_t)(nb + r) * H1DIM + ro * 256 + ch] = vv;
        }
        __syncthreads();
    }
}

// ---------------------------------------------------------------------------
// LAYER2: per graph. GEMM2 transposed (h2T in regs) + logits2 + softmax2
// + collapsed mean-pool, all fused. LDS ~13.3KB.
// ---------------------------------------------------------------------------
__global__ __launch_bounds__(256) void k_layer2(
    const unsigned short* __restrict__ x1g, const unsigned short* __restrict__ w2T,
    const float* __restrict__ as2, const float* __restrict__ ad2,
    const float* __restrict__ b2, const float* __restrict__ gl,
    const int* __restrict__ src, const int* __restrict__ dst, int epg,
    float* __restrict__ dout)
{
    __shared__ __align__(16) char S[13568];
    unsigned short* As    = (unsigned short*)S;              // [128][32] | cntI | alphaF
    int*            cntI  = (int*)S;
    float*          alphaF= (float*)S;                       // [32][33]
    unsigned short* Bs    = (unsigned short*)(S + 8448);     // [32][32]
    unsigned char*  cntB  = (unsigned char*)(S + 10496);
    float* es2P = (float*)(S + 11520);                       // [4][32]
    float* ed2P = (float*)(S + 12032);
    float* esL  = (float*)(S + 12544);                       // [32]
    float* edL  = (float*)(S + 12672);
    float* rs2L = (float*)(S + 12800);
    float* wn2  = (float*)(S + 12928);
    float* poolL= (float*)(S + 13056);                       // [128]

    const int b = blockIdx.x, t = threadIdx.x;
    const int w = t >> 6, l = t & 63;
    const int g = l >> 4, i16 = l & 15;
    const int nb = b * NF;
    const f32x4 zf4 = {0.f, 0.f, 0.f, 0.f};

    // P0: cnt (cntI aliases As; done before staging)
    for (int i = t; i < NF * NF; i += 256) cntI[i] = 0;
    __syncthreads();
    for (int i = t; i < epg; i += 256) {
        int sv = src[b * epg + i] - nb;
        int dv = dst[b * epg + i] - nb;
        atomicAdd(&cntI[dv * NF + sv], 1);
    }
    if (t < NF) atomicAdd(&cntI[t * 33], 1);
    __syncthreads();
    for (int i = t; i < NF * NF; i += 256) {
        int c = cntI[i];
        cntB[i] = (unsigned char)(c > 255 ? 255 : c);
    }
    __syncthreads();

    // P1: GEMM2T: D[f2][node] = sum_k w2T[f2][k] * x1[node][k]
    f32x4 acc[2][2];
    #pragma unroll
    for (int m = 0; m < 2; ++m)
        #pragma unroll
        for (int n = 0; n < 2; ++n) acc[m][n] = zf4;

    for (int k0 = 0; k0 < H1DIM; k0 += 32) {
        for (int i = t; i < 512; i += 256) {
            int r = i >> 2, ch = (i & 3) * 8;
            *(u16x8*)&As[st128_at(r, ch)] =
                *(const u16x8*)&w2T[(size_t)r * H1DIM + k0 + ch];
        }
        if (t < 128) {
            int r = t >> 2, ch = (t & 3) * 8;
            *(u16x8*)&Bs[st32_at(r, ch)] =
                *(const u16x8*)&x1g[(size_t)(nb + r) * H1DIM + k0 + ch];
        }
        __syncthreads();
        bf16x8 aF[2], bF[2];
        #pragma unroll
        for (int m = 0; m < 2; ++m)
            aF[m] = *(const bf16x8*)&As[st128_at(w * 32 + m * 16 + i16, g * 8)];
        #pragma unroll
        for (int n = 0; n < 2; ++n)
            bF[n] = *(const bf16x8*)&Bs[st32_at(n * 16 + i16, g * 8)];
        #pragma unroll
        for (int m = 0; m < 2; ++m)
            #pragma unroll
            for (int n = 0; n < 2; ++n)
                acc[m][n] = __builtin_amdgcn_mfma_f32_16x16x32_bf16(aF[m], bF[n], acc[m][n], 0, 0, 0);
        __syncthreads();
    }

    // P2: logits2 partials
    {
        float a2v[2][4], d2v[2][4];
        #pragma unroll
        for (int m = 0; m < 2; ++m)
            #pragma unroll
            for (int v = 0; v < 4; ++v) {
                int f2 = w * 32 + m * 16 + g * 4 + v;
                a2v[m][v] = as2[f2]; d2v[m][v] = ad2[f2];
            }
        #pragma unroll
        for (int n = 0; n < 2; ++n) {
            float e = 0.f, d = 0.f;
            #pragma unroll
            for (int m = 0; m < 2; ++m)
                #pragma unroll
                for (int v = 0; v < 4; ++v) {
                    e = fmaf(acc[m][n][v], a2v[m][v], e);
                    d = fmaf(acc[m][n][v], d2v[m][v], d);
                }
            e += __shfl_xor(e, 16); e += __shfl_xor(e, 32);
            d += __shfl_xor(d, 16); d += __shfl_xor(d, 32);
            if (g == 0) {
                es2P[w * 32 + n * 16 + i16] = e;
                ed2P[w * 32 + n * 16 + i16] = d;
            }
        }
    }
    __syncthreads();
    if (t < NF) {
        esL[t] = es2P[t] + es2P[32 + t] + es2P[64 + t] + es2P[96 + t];
        edL[t] = ed2P[t] + ed2P[32 + t] + ed2P[64 + t] + ed2P[96 + t];
    }
    __syncthreads();

    // P3: softmax2 (alphaF aliases As region — GEMM done)
    if (t < NF) {
        int d = t;
        float edv = edL[d];
        float mx = -INFINITY;
        #pragma unroll
        for (int s = 0; s < NF; ++s) {
            if (cntB[d * NF + s]) {
                float lg = esL[s] + edv;
                lg = fmaxf(lg, 0.2f * lg);
                mx = fmaxf(mx, lg);
            }
        }
        float sum = 0.f;
        #pragma unroll
        for (int s = 0; s < NF; ++s) {
            int c = cntB[d * NF + s];
            float a = 0.f;
            if (c) {
                float lg = esL[s] + edv;
                lg = fmaxf(lg, 0.2f * lg);
                a = (float)c * __expf(lg - mx);
                sum += a;
            }
            alphaF[d * 33 + s] = a;
        }
        rs2L[d] = 1.0f / sum;
    }
    __syncthreads();
    if (t < NF) {
        float a = 0.f;
        #pragma unroll
        for (int d = 0; d < NF; ++d) a = fmaf(alphaF[d * 33 + t], rs2L[d], a);
        wn2[t] = a;
    }
    __syncthreads();

    // P4: pool = sum_s wn2[s] * h2T[f2][s] (from registers)
    {
        float wv[2];
        #pragma unroll
        for (int n = 0; n < 2; ++n) wv[n] = wn2[n * 16 + i16];
        #pragma unroll
        for (int m = 0; m < 2; ++m)
            #pragma unroll
            for (int v = 0; v < 4; ++v) {
                float p = wv[0] * acc[m][0][v] + wv[1] * acc[m][1][v];
                #pragma unroll
                for (int o = 1; o < 16; o <<= 1) p += __shfl_xor(p, o);
                if (i16 == 0) poolL[w * 32 + m * 16 + g * 4 + v] = p;
            }
    }
    __syncthreads();
    if (t < HID)
        dout[(size_t)b * HID + t] = poolL[t] * (1.0f / NF) + b2[t];
    if (b == 0 && t >= 128 && t < 128 + NF)
        dout[(size_t)NB * HID + (t - 128)] = 1.0f / (1.0f + __expf(-gl[t - 128]));
}

// ---------------------------------------------------------------------------
extern "C" void kernel_launch(void* const* d_in, const int* in_sizes, int n_in,
                              void* d_out, int out_size, void* d_ws, size_t ws_size,
                              hipStream_t stream)
{
    const float* xf    = (const float*)d_in[0];
    const float* Wa    = (const float*)d_in[1];
    const float* ba    = (const float*)d_in[2];
    const float* gamma = (const float*)d_in[3];
    const float* beta  = (const float*)d_in[4];
    const float* gl    = (const float*)d_in[5];
    const float* w1    = (const float*)d_in[6];
    const float* as1   = (const float*)d_in[7];
    const float* ad1   = (const float*)d_in[8];
    const float* b1    = (const float*)d_in[9];
    const float* w2    = (const float*)d_in[10];
    const float* as2   = (const float*)d_in[11];
    const float* ad2   = (const float*)d_in[12];
    const float* b2    = (const float*)d_in[13];
    const int*   eidx  = (const int*)d_in[14];
    const int E = in_sizes[14] / 2;
    const int* srcG = eidx;
    const int* dstG = eidx + E;
    const int epg = (E - NTOT) / NB;

    char* w = (char*)d_ws;
    unsigned short* w1T = (unsigned short*)w; w += (size_t)H1DIM * HID * 2;
    unsigned short* w2T = (unsigned short*)w; w += (size_t)HID * H1DIM * 2;
    unsigned short* WaT = (unsigned short*)w; w += (size_t)HID * DIN * 2;
    unsigned short* x0b = (unsigned short*)w; w += (size_t)NTOT * HID * 2;      // 8 MB
    unsigned short* h1t = (unsigned short*)w; w += (size_t)NB * 512 * 32 * 2;   // 32 MB
    unsigned short* x1g = (unsigned short*)w; w += (size_t)NTOT * H1DIM * 2;    // 32 MB
    float* es1          = (float*)w;          w += (size_t)NTOT * HEADS * 4;
    float* ed1          = (float*)w;          w += (size_t)NTOT * HEADS * 4;

    k_prep<<<(2 * HID * H1DIM + DIN * HID) / 256, 256, 0, stream>>>(
        w1, w2, Wa, w1T, w2T, WaT);

    k_align<<<NTOT / 32, 256, 0, stream>>>(xf, WaT, ba, gamma, beta, gl, x0b);

    k_gemm1<<<dim3(HEADS, NTOT / 128), 256, 0, stream>>>(
        x0b, w1T, as1, ad1, h1t, es1, ed1);

    k_gat1<<<NB, 256, 0, stream>>>(h1t, es1, ed1, b1, srcG, dstG, epg, x1g);

    k_layer2<<<NB, 256, 0, stream>>>(
        x1g, w2T, as2, ad2, b2, gl, srcG, dstG, epg, (float*)d_out);
}